// Round 1
// baseline (2673.164 us; speedup 1.0000x reference)
//
#include <hip/hip_runtime.h>
#include <stdint.h>

#define NTHREADS 256
#define KTOP 50
#define NBINS 8192
#define CAP 4096
#define EPSV 1e-8f

// NOTE: assumes V < 65536 (here V=50257) so indices fit u16.

__device__ __forceinline__ void row_pass_hist(
    const float* __restrict__ row, int V,
    int use_prefix, uint32_t cur_shift, uint32_t cur_prefix,
    uint32_t nb_shift, uint32_t bmask, uint32_t* hist)
{
    const int tid = threadIdx.x;
    int mis = (int)(((uintptr_t)row >> 2) & 3);
    int head = (4 - mis) & 3; if (head > V) head = V;
    auto proc = [&](uint32_t key) {
        if (!use_prefix || (key >> cur_shift) == cur_prefix)
            atomicAdd(&hist[(key >> nb_shift) & bmask], 1u);
    };
    if (tid < head) proc(__float_as_uint(row[tid]));
    int nvec = (V - head) >> 2;
    const float4* vrow = reinterpret_cast<const float4*>(row + head);
    for (int i = tid; i < nvec; i += NTHREADS) {
        float4 v = vrow[i];
        proc(__float_as_uint(v.x)); proc(__float_as_uint(v.y));
        proc(__float_as_uint(v.z)); proc(__float_as_uint(v.w));
    }
    for (int i = head + (nvec << 2) + tid; i < V; i += NTHREADS)
        proc(__float_as_uint(row[i]));
}

__device__ __forceinline__ void row_pass_collect(
    const float* __restrict__ row, int V, uint32_t lo_key,
    uint32_t* cand_key, uint16_t* cand_idx, uint32_t* s_count)
{
    const int tid = threadIdx.x;
    int mis = (int)(((uintptr_t)row >> 2) & 3);
    int head = (4 - mis) & 3; if (head > V) head = V;
    auto proc = [&](uint32_t key, int idx) {
        if (key >= lo_key) {
            uint32_t pos = atomicAdd(s_count, 1u);
            if (pos < CAP) { cand_key[pos] = key; cand_idx[pos] = (uint16_t)idx; }
        }
    };
    if (tid < head) proc(__float_as_uint(row[tid]), tid);
    int nvec = (V - head) >> 2;
    const float4* vrow = reinterpret_cast<const float4*>(row + head);
    for (int i = tid; i < nvec; i += NTHREADS) {
        float4 v = vrow[i];
        int b = head + (i << 2);
        proc(__float_as_uint(v.x), b);     proc(__float_as_uint(v.y), b + 1);
        proc(__float_as_uint(v.z), b + 2); proc(__float_as_uint(v.w), b + 3);
    }
    for (int i = head + (nvec << 2) + tid; i < V; i += NTHREADS)
        proc(__float_as_uint(row[i]), i);
}

// Exact top-K (value desc, index asc tie-break, matching jax.lax.top_k).
__device__ void select_topk(const float* __restrict__ row, int V,
    uint32_t* hist, uint32_t* cand_key, uint16_t* cand_idx,
    uint32_t* partial, uint32_t* suffixs, uint32_t* s_misc,
    unsigned long long* s_wred, uint16_t* topk)
{
    const int tid = threadIdx.x;
    uint32_t cur_shift = 32, cur_prefix = 0, c_hi = 0;
    int need = KTOP;
    uint32_t lo_key = 0;
    int first = 1;

    while (true) {
        uint32_t nb_shift = (cur_shift > 13) ? (cur_shift - 13) : 0;
        uint32_t nbits = cur_shift - nb_shift;
        uint32_t nbins = 1u << nbits;
        uint32_t bmask = nbins - 1;

        for (uint32_t b = tid; b < nbins; b += NTHREADS) hist[b] = 0;
        __syncthreads();
        row_pass_hist(row, V, !first, cur_shift, cur_prefix, nb_shift, bmask, hist);
        __syncthreads();

        uint32_t R = (nbins + NTHREADS - 1) / NTHREADS;
        uint32_t lo_b = tid * R;
        uint32_t hi_b = lo_b + R; if (hi_b > nbins) hi_b = nbins;
        uint32_t ps = 0;
        if (lo_b < nbins) for (uint32_t b = lo_b; b < hi_b; ++b) ps += hist[b];
        partial[tid] = ps;
        __syncthreads();
        if (tid == 0) {
            uint32_t run = 0;
            for (int t = NTHREADS - 1; t >= 0; --t) { suffixs[t] = run; run += partial[t]; }
        }
        __syncthreads();
        if (lo_b < nbins) {
            uint32_t run = suffixs[tid];
            for (int b = (int)hi_b - 1; b >= (int)lo_b; --b) {
                uint32_t c = hist[b];
                if (run < (uint32_t)need && run + c >= (uint32_t)need) {
                    s_misc[0] = (uint32_t)b;  // threshold bin T
                    s_misc[1] = run;          // in-range count above T
                }
                run += c;
            }
        }
        __syncthreads();
        uint32_t T = s_misc[0], cab = s_misc[1];
        uint32_t histT = hist[T];
        __syncthreads();   // everyone has read hist[T]/s_misc before reuse

        c_hi += cab; need -= (int)cab;
        cur_prefix = (cur_prefix << nbits) | T;
        cur_shift = nb_shift;
        lo_key = cur_prefix << cur_shift;
        first = 0;
        if (c_hi + histT <= CAP || cur_shift == 0) break;
    }

    if (tid == 0) s_misc[2] = 0;
    __syncthreads();
    row_pass_collect(row, V, lo_key, cand_key, cand_idx, &s_misc[2]);
    __syncthreads();
    uint32_t nc = s_misc[2]; if (nc > CAP) nc = CAP;

    for (int k = 0; k < KTOP; ++k) {
        unsigned long long best = 0;
        for (uint32_t j = tid; j < nc; j += NTHREADS) {
            unsigned long long comp =
                ((unsigned long long)cand_key[j] << 16) |
                (unsigned long long)(0xFFFFu - (uint32_t)cand_idx[j]);
            if (comp > best) best = comp;
        }
        for (int off = 32; off; off >>= 1) {
            unsigned long long o = __shfl_down(best, off);
            if (o > best) best = o;
        }
        if ((tid & 63) == 0) s_wred[tid >> 6] = best;
        __syncthreads();
        if (tid == 0) {
            unsigned long long b0 = s_wred[0];
            for (int w = 1; w < NTHREADS / 64; ++w)
                if (s_wred[w] > b0) b0 = s_wred[w];
            s_wred[4] = b0;
        }
        __syncthreads();
        unsigned long long b = s_wred[4];
        uint32_t wkey = (uint32_t)(b >> 16);
        uint16_t widx = (uint16_t)(0xFFFFu - (uint32_t)(b & 0xFFFFu));
        if (tid == 0) topk[k] = widx;
        for (uint32_t j = tid; j < nc; j += NTHREADS) {
            if (cand_key[j] == wkey && cand_idx[j] == widx) {
                cand_key[j] = 0; cand_idx[j] = 0xFFFFu;
            }
        }
        __syncthreads();
    }
}

__global__ __launch_bounds__(NTHREADS)
void topk_jsd_kernel(const float* __restrict__ p, const float* __restrict__ q,
                     float* __restrict__ out, int V)
{
    __shared__ uint32_t hist[NBINS];
    __shared__ uint32_t cand_key[CAP];
    __shared__ uint16_t cand_idx[CAP];
    __shared__ uint32_t partial[NTHREADS];
    __shared__ uint32_t suffixs[NTHREADS];
    __shared__ unsigned long long s_wred[8];
    __shared__ uint32_t s_misc[4];
    __shared__ uint16_t topk_p[KTOP];
    __shared__ uint16_t topk_q[KTOP];
    __shared__ uint16_t s_union[2 * KTOP];
    __shared__ int s_nu;
    __shared__ float s_fred[8];

    const int row = blockIdx.x;
    const int tid = threadIdx.x;
    const float* prow = p + (size_t)row * (size_t)V;
    const float* qrow = q + (size_t)row * (size_t)V;

    select_topk(prow, V, hist, cand_key, cand_idx, partial, suffixs, s_misc, s_wred, topk_p);
    __syncthreads();
    select_topk(qrow, V, hist, cand_key, cand_idx, partial, suffixs, s_misc, s_wred, topk_q);
    __syncthreads();

    // union of the two top-K index sets (wave 0)
    if (tid < KTOP) s_union[tid] = topk_p[tid];
    __syncthreads();
    if (tid < 64) {
        bool fresh = false; uint16_t qi = 0;
        if (tid < KTOP) {
            qi = topk_q[tid]; fresh = true;
            for (int j = 0; j < KTOP; ++j) if (topk_p[j] == qi) fresh = false;
        }
        unsigned long long m = __ballot(fresh);
        int pos = __popcll(m & ((1ull << tid) - 1ull));
        if (fresh) s_union[KTOP + pos] = qi;
        if (tid == 0) s_nu = KTOP + __popcll(m);
    }
    __syncthreads();
    int nu = s_nu;

    float pv = 0.f, qv = 0.f;
    if (tid < nu) {
        int ui = s_union[tid];
        pv = prow[ui];
        qv = qrow[ui];
    }

    // block-reduce masked sums
    float sp = pv, sq = qv;
    for (int off = 32; off; off >>= 1) { sp += __shfl_down(sp, off); sq += __shfl_down(sq, off); }
    int wid = tid >> 6;
    if ((tid & 63) == 0) { s_fred[wid] = sp; s_fred[4 + wid] = sq; }
    __syncthreads();
    if (tid == 0) {
        float a = 0.f, b = 0.f;
        for (int w = 0; w < NTHREADS / 64; ++w) { a += s_fred[w]; b += s_fred[4 + w]; }
        s_fred[0] = a; s_fred[4] = b;
    }
    __syncthreads();
    float sump = s_fred[0], sumq = s_fred[4];
    __syncthreads();

    float term = 0.f;
    if (tid < nu) {
        float pn = pv / (sump + EPSV);
        float qn = qv / (sumq + EPSV);
        float mn = 0.5f * (pn + qn);
        float ps = pn + EPSV, qs = qn + EPSV, ms = mn + EPSV;
        term = 0.5f * (ps * logf(ps / ms) + qs * logf(qs / ms));
    }
    for (int off = 32; off; off >>= 1) term += __shfl_down(term, off);
    if ((tid & 63) == 0) s_fred[wid] = term;
    __syncthreads();
    if (tid == 0) {
        float a = 0.f;
        for (int w = 0; w < NTHREADS / 64; ++w) a += s_fred[w];
        out[row] = a;
    }
}

extern "C" void kernel_launch(void* const* d_in, const int* in_sizes, int n_in,
                              void* d_out, int out_size, void* d_ws, size_t ws_size,
                              hipStream_t stream) {
    const float* p = (const float*)d_in[0];
    const float* q = (const float*)d_in[1];
    float* out = (float*)d_out;
    if (out_size <= 0) return;
    int N = out_size;                 // B*S rows
    int V = in_sizes[0] / N;          // vocab size per row
    topk_jsd_kernel<<<dim3(N), dim3(NTHREADS), 0, stream>>>(p, q, out, V);
}

// Round 2
// 803.719 us; speedup vs baseline: 3.3260x; 3.3260x over previous
//
#include <hip/hip_runtime.h>
#include <stdint.h>

#define NTHREADS 256
#define KTOP 50
#define CAP 1024
#define EPSV 1e-8f

typedef unsigned long long u64;

// ---- block-wide float max (s_f: 8 floats scratch) ----
__device__ __forceinline__ float block_max(float v, float* s_f, int tid) {
    for (int off = 32; off; off >>= 1) v = fmaxf(v, __shfl_down(v, off));
    if ((tid & 63) == 0) s_f[tid >> 6] = v;
    __syncthreads();
    if (tid == 0) {
        float m = s_f[0];
        for (int w = 1; w < NTHREADS / 64; ++w) m = fmaxf(m, s_f[w]);
        s_f[4] = m;
    }
    __syncthreads();
    float r = s_f[4];
    __syncthreads();   // s_f reused by later calls
    return r;
}

// ---- streaming row max, float4-vectorized with alignment peel ----
__device__ float row_max_stream(const float* __restrict__ row, int V, int tid) {
    float m = 0.f;
    int mis = (int)(((uintptr_t)row >> 2) & 3);
    int head = (4 - mis) & 3; if (head > V) head = V;
    if (tid < head) m = fmaxf(m, row[tid]);
    int nvec = (V - head) >> 2;
    const float4* vr = reinterpret_cast<const float4*>(row + head);
    for (int i = tid; i < nvec; i += NTHREADS) {
        float4 v = vr[i];
        m = fmaxf(fmaxf(m, fmaxf(v.x, v.y)), fmaxf(v.z, v.w));
    }
    for (int i = head + (nvec << 2) + tid; i < V; i += NTHREADS)
        m = fmaxf(m, row[i]);
    return m;
}

// ---- collect all elements >= t as composites into LDS; returns count ----
__device__ int collect(const float* __restrict__ row, int V, float t,
                       u64* cand, uint32_t* s_cnt, int tid) {
    if (tid == 0) *s_cnt = 0;
    __syncthreads();
    auto proc = [&](float v, int idx) {
        if (v >= t) {
            uint32_t pos = atomicAdd(s_cnt, 1u);
            if (pos < CAP)
                cand[pos] = (((u64)__float_as_uint(v)) << 16) |
                            (u64)(0xFFFFu - (uint32_t)idx);
        }
    };
    int mis = (int)(((uintptr_t)row >> 2) & 3);
    int head = (4 - mis) & 3; if (head > V) head = V;
    if (tid < head) proc(row[tid], tid);
    int nvec = (V - head) >> 2;
    const float4* vr = reinterpret_cast<const float4*>(row + head);
    for (int i = tid; i < nvec; i += NTHREADS) {
        float4 v = vr[i];
        int b = head + (i << 2);
        proc(v.x, b); proc(v.y, b + 1); proc(v.z, b + 2); proc(v.w, b + 3);
    }
    for (int i = head + (nvec << 2) + tid; i < V; i += NTHREADS)
        proc(row[i], i);
    __syncthreads();
    int n = (int)*s_cnt;
    __syncthreads();   // guard s_cnt reuse by next collect
    return n;
}

// ---- exact top-K: K block-argmax iterations, register-cached local max ----
// Winners' indices written to top[0..K). Destroys cand entries of winners.
__device__ void find_topk(u64* cand, int nc, uint16_t* top, u64* s_w, int tid) {
    u64 lmax = 0; int lpos = -1;
    for (int j = tid; j < nc; j += NTHREADS) {
        u64 c = cand[j];
        if (c > lmax) { lmax = c; lpos = j; }
    }
    for (int k = 0; k < KTOP; ++k) {
        u64 m = lmax;
        #pragma unroll
        for (int off = 32; off; off >>= 1) {
            u64 o = __shfl_down(m, off);
            if (o > m) m = o;
        }
        if ((tid & 63) == 0) s_w[tid >> 6] = m;
        __syncthreads();
        if (tid == 0) {
            u64 b = s_w[0];
            for (int w = 1; w < NTHREADS / 64; ++w) if (s_w[w] > b) b = s_w[w];
            s_w[4 + (k & 1)] = b;                       // double-buffered broadcast
            top[k] = (uint16_t)(0xFFFFu - (uint32_t)(b & 0xFFFFu));
        }
        __syncthreads();
        u64 wmax = s_w[4 + (k & 1)];
        if (k < KTOP - 1 && lmax == wmax && lpos >= 0) {  // unique winner rescans
            cand[lpos] = 0;
            lmax = 0; lpos = -1;
            for (int j = tid; j < nc; j += NTHREADS) {
                u64 c = cand[j];
                if (c > lmax) { lmax = c; lpos = j; }
            }
        }
    }
    __syncthreads();
}

__global__ __launch_bounds__(NTHREADS)
void topk_jsd_kernel(const float* __restrict__ p, const float* __restrict__ q,
                     float* __restrict__ out, int V)
{
    __shared__ u64 candP[CAP];
    __shared__ u64 candQ[CAP];
    __shared__ u64 s_w[8];
    __shared__ float s_f[8];
    __shared__ uint32_t s_cnt;
    __shared__ uint16_t topP[KTOP];
    __shared__ uint16_t topQ[KTOP];
    __shared__ uint16_t s_union[2 * KTOP];
    __shared__ int s_nu;

    const int row = blockIdx.x;
    const int tid = threadIdx.x;
    const float* prow = p + (size_t)row * (size_t)V;
    const float* qrow = q + (size_t)row * (size_t)V;

    // pass 1: row maxima
    float MP = block_max(row_max_stream(prow, V, tid), s_f, tid);
    float MQ = block_max(row_max_stream(qrow, V, tid), s_f, tid);

    // pass 2: threshold-collect with verification/retry
    float eps0 = fminf(600.f / (float)V, 0.5f);
    float epsP = eps0, epsQ = eps0;
    int ncP = collect(prow, V, MP * (1.f - epsP), candP, &s_cnt, tid);
    for (int a = 0; a < 10 && (ncP < KTOP || ncP > CAP); ++a) {
        epsP = (ncP > CAP) ? epsP * 0.25f : fminf(epsP * 4.f, 1.f);
        ncP = collect(prow, V, MP * (1.f - epsP), candP, &s_cnt, tid);
    }
    if (ncP > CAP) ncP = CAP;
    int ncQ = collect(qrow, V, MQ * (1.f - epsQ), candQ, &s_cnt, tid);
    for (int a = 0; a < 10 && (ncQ < KTOP || ncQ > CAP); ++a) {
        epsQ = (ncQ > CAP) ? epsQ * 0.25f : fminf(epsQ * 4.f, 1.f);
        ncQ = collect(qrow, V, MQ * (1.f - epsQ), candQ, &s_cnt, tid);
    }
    if (ncQ > CAP) ncQ = CAP;

    // exact top-50 of each (value desc, index asc — matches jax.lax.top_k)
    find_topk(candP, ncP, topP, s_w, tid);
    find_topk(candQ, ncQ, topQ, s_w, tid);

    // union of index sets (wave 0)
    if (tid < KTOP) s_union[tid] = topP[tid];
    __syncthreads();
    if (tid < 64) {
        bool fresh = false; uint16_t qi = 0;
        if (tid < KTOP) {
            qi = topQ[tid]; fresh = true;
            for (int j = 0; j < KTOP; ++j) if (topP[j] == qi) fresh = false;
        }
        unsigned long long mb = __ballot(fresh);
        int pos = __popcll(mb & ((1ull << tid) - 1ull));
        if (fresh) s_union[KTOP + pos] = qi;
        if (tid == 0) s_nu = KTOP + __popcll(mb);
    }
    __syncthreads();
    int nu = s_nu;

    // gather union values
    float pv = 0.f, qv = 0.f;
    if (tid < nu) {
        int ui = s_union[tid];
        pv = prow[ui];
        qv = qrow[ui];
    }

    // block-reduce masked sums
    float sp = pv, sq = qv;
    for (int off = 32; off; off >>= 1) { sp += __shfl_down(sp, off); sq += __shfl_down(sq, off); }
    int wid = tid >> 6;
    if ((tid & 63) == 0) { s_f[wid] = sp; s_f[4 + wid] = sq; }
    __syncthreads();
    if (tid == 0) {
        float a = 0.f, b = 0.f;
        for (int w = 0; w < NTHREADS / 64; ++w) { a += s_f[w]; b += s_f[4 + w]; }
        s_f[0] = a; s_f[4] = b;
    }
    __syncthreads();
    float sump = s_f[0], sumq = s_f[4];
    __syncthreads();

    // JSD over union (identical formula to validated R1 kernel)
    float term = 0.f;
    if (tid < nu) {
        float pn = pv / (sump + EPSV);
        float qn = qv / (sumq + EPSV);
        float mn = 0.5f * (pn + qn);
        float ps = pn + EPSV, qs = qn + EPSV, ms = mn + EPSV;
        term = 0.5f * (ps * logf(ps / ms) + qs * logf(qs / ms));
    }
    for (int off = 32; off; off >>= 1) term += __shfl_down(term, off);
    if ((tid & 63) == 0) s_f[wid] = term;
    __syncthreads();
    if (tid == 0) {
        float a = 0.f;
        for (int w = 0; w < NTHREADS / 64; ++w) a += s_f[w];
        out[row] = a;
    }
}

extern "C" void kernel_launch(void* const* d_in, const int* in_sizes, int n_in,
                              void* d_out, int out_size, void* d_ws, size_t ws_size,
                              hipStream_t stream) {
    const float* p = (const float*)d_in[0];
    const float* q = (const float*)d_in[1];
    float* out = (float*)d_out;
    if (out_size <= 0) return;
    int N = out_size;            // B*S rows
    int V = in_sizes[0] / N;     // vocab size
    topk_jsd_kernel<<<dim3(N), dim3(NTHREADS), 0, stream>>>(p, q, out, V);
}

// Round 3
// 569.508 us; speedup vs baseline: 4.6938x; 1.4113x over previous
//
#include <hip/hip_runtime.h>
#include <stdint.h>

#define NTHREADS 256
#define KTOP 50
#define CAP 1024
#define EPSV 1e-8f

typedef unsigned long long u64;

// ---- block-wide float max (s_f: 8 floats scratch) ----
__device__ __forceinline__ float block_max(float v, float* s_f, int tid) {
    for (int off = 32; off; off >>= 1) v = fmaxf(v, __shfl_down(v, off));
    if ((tid & 63) == 0) s_f[tid >> 6] = v;
    __syncthreads();
    if (tid == 0) {
        float m = s_f[0];
        for (int w = 1; w < NTHREADS / 64; ++w) m = fmaxf(m, s_f[w]);
        s_f[4] = m;
    }
    __syncthreads();
    float r = s_f[4];
    __syncthreads();   // s_f reused by later calls
    return r;
}

// ---- fused streaming pass: collect v >= t AND track thread-local max ----
__device__ float collect_max(const float* __restrict__ row, int V, float t,
                             u64* cand, uint32_t* s_cnt, int tid) {
    float m = 0.f;
    auto proc = [&](float v, int idx) {
        m = fmaxf(m, v);
        if (v >= t) {
            uint32_t pos = atomicAdd(s_cnt, 1u);
            if (pos < CAP)
                cand[pos] = (((u64)__float_as_uint(v)) << 16) |
                            (u64)(0xFFFFu - (uint32_t)idx);
        }
    };
    int mis = (int)(((uintptr_t)row >> 2) & 3);
    int head = (4 - mis) & 3; if (head > V) head = V;
    if (tid < head) proc(row[tid], tid);
    int nvec = (V - head) >> 2;
    const float4* vr = reinterpret_cast<const float4*>(row + head);
    #pragma unroll 4
    for (int i = tid; i < nvec; i += NTHREADS) {
        float4 v = vr[i];
        int b = head + (i << 2);
        proc(v.x, b); proc(v.y, b + 1); proc(v.z, b + 2); proc(v.w, b + 3);
    }
    for (int i = head + (nvec << 2) + tid; i < V; i += NTHREADS)
        proc(row[i], i);
    return m;
}

// ---- run one collect pass (zero counter, pass, return count & true max) ----
__device__ int do_collect(const float* __restrict__ row, int V, float t,
                          u64* cand, uint32_t* s_cnt, float* s_f,
                          float* trueMax, int tid) {
    if (tid == 0) *s_cnt = 0;
    __syncthreads();
    float lm = collect_max(row, V, t, cand, s_cnt, tid);
    __syncthreads();
    int n = (int)*s_cnt;
    __syncthreads();
    *trueMax = block_max(lm, s_f, tid);
    return n;
}

// ---- exact top-K: K block-argmax iterations, register-cached local max ----
__device__ void find_topk(u64* cand, int nc, uint16_t* top, u64* s_w, int tid) {
    u64 lmax = 0; int lpos = -1;
    for (int j = tid; j < nc; j += NTHREADS) {
        u64 c = cand[j];
        if (c > lmax) { lmax = c; lpos = j; }
    }
    for (int k = 0; k < KTOP; ++k) {
        u64 m = lmax;
        #pragma unroll
        for (int off = 32; off; off >>= 1) {
            u64 o = __shfl_down(m, off);
            if (o > m) m = o;
        }
        if ((tid & 63) == 0) s_w[tid >> 6] = m;
        __syncthreads();
        if (tid == 0) {
            u64 b = s_w[0];
            for (int w = 1; w < NTHREADS / 64; ++w) if (s_w[w] > b) b = s_w[w];
            s_w[4 + (k & 1)] = b;                       // double-buffered broadcast
            top[k] = (uint16_t)(0xFFFFu - (uint32_t)(b & 0xFFFFu));
        }
        __syncthreads();
        u64 wmax = s_w[4 + (k & 1)];
        if (k < KTOP - 1 && lmax == wmax && lpos >= 0) {  // unique winner rescans
            cand[lpos] = 0;
            lmax = 0; lpos = -1;
            for (int j = tid; j < nc; j += NTHREADS) {
                u64 c = cand[j];
                if (c > lmax) { lmax = c; lpos = j; }
            }
        }
    }
    __syncthreads();
}

__global__ __launch_bounds__(NTHREADS)
void topk_jsd_kernel(const float* __restrict__ p, const float* __restrict__ q,
                     float* __restrict__ out, int V)
{
    __shared__ u64 candP[CAP];
    __shared__ u64 candQ[CAP];
    __shared__ u64 s_w[8];
    __shared__ float s_f[8];
    __shared__ uint32_t s_cnt;
    __shared__ uint16_t topP[KTOP];
    __shared__ uint16_t topQ[KTOP];
    __shared__ uint16_t s_union[2 * KTOP];
    __shared__ int s_nu;

    const int row = blockIdx.x;
    const int tid = threadIdx.x;
    const float* prow = p + (size_t)row * (size_t)V;
    const float* qrow = q + (size_t)row * (size_t)V;

    // ---- sample phase: max of first SMP elements (contiguous -> L2-warm) ----
    int smp = V < 2048 ? V : 2048;
    float msP = 0.f, msQ = 0.f;
    for (int i = tid; i < smp; i += NTHREADS) {
        msP = fmaxf(msP, prow[i]);
        msQ = fmaxf(msQ, qrow[i]);
    }
    float MsP = block_max(msP, s_f, tid);
    float MsQ = block_max(msQ, s_f, tid);

    // target ~650 candidates: eps = 600/V + 1/smp (compensates sample-max bias)
    float eps0 = fminf(600.f / (float)V + 1.f / (float)smp, 0.5f);

    // ---- single full pass: collect + true max (retry never taken on sane data) ----
    float MP, MQ;
    float epsP = eps0;
    int ncP = do_collect(prow, V, MsP * (1.f - epsP), candP, &s_cnt, s_f, &MP, tid);
    for (int a = 0; a < 10 && (ncP < KTOP || ncP > CAP); ++a) {
        epsP = (ncP > CAP) ? epsP * 0.25f : fminf(epsP * 4.f, 1.f);
        ncP = do_collect(prow, V, MP * (1.f - epsP), candP, &s_cnt, s_f, &MP, tid);
    }
    if (ncP > CAP) ncP = CAP;

    float epsQ = eps0;
    int ncQ = do_collect(qrow, V, MsQ * (1.f - epsQ), candQ, &s_cnt, s_f, &MQ, tid);
    for (int a = 0; a < 10 && (ncQ < KTOP || ncQ > CAP); ++a) {
        epsQ = (ncQ > CAP) ? epsQ * 0.25f : fminf(epsQ * 4.f, 1.f);
        ncQ = do_collect(qrow, V, MQ * (1.f - epsQ), candQ, &s_cnt, s_f, &MQ, tid);
    }
    if (ncQ > CAP) ncQ = CAP;

    // ---- exact top-50 of each (value desc, index asc — matches jax.lax.top_k) ----
    find_topk(candP, ncP, topP, s_w, tid);
    find_topk(candQ, ncQ, topQ, s_w, tid);

    // ---- union of index sets (wave 0) ----
    if (tid < KTOP) s_union[tid] = topP[tid];
    __syncthreads();
    if (tid < 64) {
        bool fresh = false; uint16_t qi = 0;
        if (tid < KTOP) {
            qi = topQ[tid]; fresh = true;
            for (int j = 0; j < KTOP; ++j) if (topP[j] == qi) fresh = false;
        }
        unsigned long long mb = __ballot(fresh);
        int pos = __popcll(mb & ((1ull << tid) - 1ull));
        if (fresh) s_union[KTOP + pos] = qi;
        if (tid == 0) s_nu = KTOP + __popcll(mb);
    }
    __syncthreads();
    int nu = s_nu;

    // ---- gather union values ----
    float pv = 0.f, qv = 0.f;
    if (tid < nu) {
        int ui = s_union[tid];
        pv = prow[ui];
        qv = qrow[ui];
    }

    // ---- block-reduce masked sums ----
    float sp = pv, sq = qv;
    for (int off = 32; off; off >>= 1) { sp += __shfl_down(sp, off); sq += __shfl_down(sq, off); }
    int wid = tid >> 6;
    if ((tid & 63) == 0) { s_f[wid] = sp; s_f[4 + wid] = sq; }
    __syncthreads();
    if (tid == 0) {
        float a = 0.f, b = 0.f;
        for (int w = 0; w < NTHREADS / 64; ++w) { a += s_f[w]; b += s_f[4 + w]; }
        s_f[0] = a; s_f[4] = b;
    }
    __syncthreads();
    float sump = s_f[0], sumq = s_f[4];
    __syncthreads();

    // ---- JSD over union (identical formula to validated kernels) ----
    float term = 0.f;
    if (tid < nu) {
        float pn = pv / (sump + EPSV);
        float qn = qv / (sumq + EPSV);
        float mn = 0.5f * (pn + qn);
        float ps = pn + EPSV, qs = qn + EPSV, ms = mn + EPSV;
        term = 0.5f * (ps * logf(ps / ms) + qs * logf(qs / ms));
    }
    for (int off = 32; off; off >>= 1) term += __shfl_down(term, off);
    if ((tid & 63) == 0) s_f[wid] = term;
    __syncthreads();
    if (tid == 0) {
        float a = 0.f;
        for (int w = 0; w < NTHREADS / 64; ++w) a += s_f[w];
        out[row] = a;
    }
}

extern "C" void kernel_launch(void* const* d_in, const int* in_sizes, int n_in,
                              void* d_out, int out_size, void* d_ws, size_t ws_size,
                              hipStream_t stream) {
    const float* p = (const float*)d_in[0];
    const float* q = (const float*)d_in[1];
    float* out = (float*)d_out;
    if (out_size <= 0) return;
    int N = out_size;            // B*S rows
    int V = in_sizes[0] / N;     // vocab size
    topk_jsd_kernel<<<dim3(N), dim3(NTHREADS), 0, stream>>>(p, q, out, V);
}

// Round 4
// 504.715 us; speedup vs baseline: 5.2964x; 1.1284x over previous
//
#include <hip/hip_runtime.h>
#include <stdint.h>

#define NTHREADS 256
#define KTOP 50
#define CAP 1024
#define CAPREF 768
#define EPSV 1e-8f

typedef unsigned long long u64;

// ---- block-wide float max (s_f: 8 floats scratch) ----
__device__ __forceinline__ float block_max(float v, float* s_f, int tid) {
    for (int off = 32; off; off >>= 1) v = fmaxf(v, __shfl_down(v, off));
    if ((tid & 63) == 0) s_f[tid >> 6] = v;
    __syncthreads();
    if (tid == 0) {
        float m = s_f[0];
        for (int w = 1; w < NTHREADS / 64; ++w) m = fmaxf(m, s_f[w]);
        s_f[4] = m;
    }
    __syncthreads();
    float r = s_f[4];
    __syncthreads();
    return r;
}

// ---- cold path: per-element direct collect (validated R2/R3 structure) ----
__device__ int collect_direct(const float* __restrict__ row, int V, float t,
                              u64* cand, uint32_t* s_cnt, int tid) {
    if (tid == 0) *s_cnt = 0;
    __syncthreads();
    auto pushc = [&](float v, int idx) {
        if (v >= t) {
            uint32_t pos = atomicAdd(s_cnt, 1u);
            if (pos < CAP)
                cand[pos] = (((u64)__float_as_uint(v)) << 16) |
                            (u64)(0xFFFFu - (uint32_t)idx);
        }
    };
    int mis = (int)(((uintptr_t)row >> 2) & 3);
    int head = (4 - mis) & 3; if (head > V) head = V;
    if (tid < head) pushc(row[tid], tid);
    int nvec = (V - head) >> 2;
    const float4* vr = reinterpret_cast<const float4*>(row + head);
    for (int i = tid; i < nvec; i += NTHREADS) {
        float4 v = vr[i];
        int b = head + (i << 2);
        pushc(v.x, b); pushc(v.y, b + 1); pushc(v.z, b + 2); pushc(v.w, b + 3);
    }
    for (int i = head + (nvec << 2) + tid; i < V; i += NTHREADS)
        pushc(row[i], i);
    __syncthreads();
    int n = (int)*s_cnt;
    __syncthreads();
    return n;
}

// ---- hot path: 8x-float4 group-test stream + ref push + post expansion ----
// Returns candidate count, or -1 on ref overflow (caller must fall back).
__device__ int collect_fast(const float* __restrict__ row, int V, float t,
                            u64* cand, uint32_t* refs,
                            uint32_t* s_cnt, uint32_t* s_ref, int tid) {
    if (tid == 0) { *s_cnt = 0; *s_ref = 0; }
    __syncthreads();
    auto pushc = [&](float v, int idx) {
        if (v >= t) {
            uint32_t pos = atomicAdd(s_cnt, 1u);
            if (pos < CAP)
                cand[pos] = (((u64)__float_as_uint(v)) << 16) |
                            (u64)(0xFFFFu - (uint32_t)idx);
        }
    };
    int mis = (int)(((uintptr_t)row >> 2) & 3);
    int head = (4 - mis) & 3; if (head > V) head = V;
    if (tid < head) pushc(row[tid], tid);
    int nvec = (V - head) >> 2;
    const float4* vr = reinterpret_cast<const float4*>(row + head);

    const int per = 8 * NTHREADS;
    int nfull = nvec / per;
    for (int m = 0; m < nfull; ++m) {
        int base = m * per + tid;
        float4 v0 = vr[base];
        float4 v1 = vr[base + NTHREADS];
        float4 v2 = vr[base + 2 * NTHREADS];
        float4 v3 = vr[base + 3 * NTHREADS];
        float4 v4 = vr[base + 4 * NTHREADS];
        float4 v5 = vr[base + 5 * NTHREADS];
        float4 v6 = vr[base + 6 * NTHREADS];
        float4 v7 = vr[base + 7 * NTHREADS];
        float m0 = fmaxf(fmaxf(fmaxf(v0.x, v0.y), v0.z), v0.w);   // v_max3 fusable
        float m1 = fmaxf(fmaxf(fmaxf(v1.x, v1.y), v1.z), v1.w);
        float m2 = fmaxf(fmaxf(fmaxf(v2.x, v2.y), v2.z), v2.w);
        float m3 = fmaxf(fmaxf(fmaxf(v3.x, v3.y), v3.z), v3.w);
        float m4 = fmaxf(fmaxf(fmaxf(v4.x, v4.y), v4.z), v4.w);
        float m5 = fmaxf(fmaxf(fmaxf(v5.x, v5.y), v5.z), v5.w);
        float m6 = fmaxf(fmaxf(fmaxf(v6.x, v6.y), v6.z), v6.w);
        float m7 = fmaxf(fmaxf(fmaxf(v7.x, v7.y), v7.z), v7.w);
        float mx = fmaxf(fmaxf(fmaxf(m0, m1), fmaxf(m2, m3)),
                         fmaxf(fmaxf(m4, m5), fmaxf(m6, m7)));
        if (mx >= t) {
            uint32_t rpos = atomicAdd(s_ref, 1u);
            if (rpos < CAPREF) refs[rpos] = (uint32_t)base;
        }
    }
    // remainder float4s + scalar tail: direct per-element push
    for (int i = nfull * per + tid; i < nvec; i += NTHREADS) {
        float4 v = vr[i];
        int b = head + (i << 2);
        pushc(v.x, b); pushc(v.y, b + 1); pushc(v.z, b + 2); pushc(v.w, b + 3);
    }
    for (int i = head + (nvec << 2) + tid; i < V; i += NTHREADS)
        pushc(row[i], i);
    __syncthreads();
    uint32_t nref = *s_ref;
    if (nref > CAPREF) { __syncthreads(); return -1; }
    // expand refs: re-read hit groups (L2-warm) and push per-element
    int units = (int)nref * 8;
    for (int u = tid; u < units; u += NTHREADS) {
        int f4 = (int)refs[u >> 3] + (u & 7) * NTHREADS;
        float4 v = vr[f4];
        int b = head + (f4 << 2);
        pushc(v.x, b); pushc(v.y, b + 1); pushc(v.z, b + 2); pushc(v.w, b + 3);
    }
    __syncthreads();
    int n = (int)*s_cnt;
    __syncthreads();
    return n;
}

// ---- barrier-free exact top-K: per-wave extract (registers+shfl), wave0 merge
// Composite keys are unique (idx in low bits) -> at most one holder clears.
__device__ void find_topk(const u64* cand, int nc, uint16_t* top,
                          u64* s_merge, int tid) {
    int lane = tid & 63, w = tid >> 6;
    u64 r0 = 0, r1 = 0, r2 = 0, r3 = 0;
    int j0 = (w << 6) + lane;
    if (j0 < nc)       r0 = cand[j0];
    if (j0 + 256 < nc) r1 = cand[j0 + 256];
    if (j0 + 512 < nc) r2 = cand[j0 + 512];
    if (j0 + 768 < nc) r3 = cand[j0 + 768];
    for (int k = 0; k < KTOP; ++k) {
        u64 a = r0 > r1 ? r0 : r1;
        u64 b = r2 > r3 ? r2 : r3;
        u64 m = a > b ? a : b;
        #pragma unroll
        for (int off = 32; off; off >>= 1) {
            u64 o = __shfl_xor(m, off);
            if (o > m) m = o;
        }
        if (lane == 0) s_merge[w * KTOP + k] = m;
        if (r0 == m) r0 = 0; else if (r1 == m) r1 = 0;
        else if (r2 == m) r2 = 0; else if (r3 == m) r3 = 0;
    }
    __syncthreads();
    if (w == 0) {
        u64 q0 = 0, q1 = 0, q2 = 0, q3 = 0;
        if (lane < 4 * KTOP)       q0 = s_merge[lane];
        if (lane + 64 < 4 * KTOP)  q1 = s_merge[lane + 64];
        if (lane + 128 < 4 * KTOP) q2 = s_merge[lane + 128];
        if (lane + 192 < 4 * KTOP) q3 = s_merge[lane + 192];
        for (int k = 0; k < KTOP; ++k) {
            u64 a = q0 > q1 ? q0 : q1;
            u64 b = q2 > q3 ? q2 : q3;
            u64 m = a > b ? a : b;
            #pragma unroll
            for (int off = 32; off; off >>= 1) {
                u64 o = __shfl_xor(m, off);
                if (o > m) m = o;
            }
            if (lane == 0) top[k] = (uint16_t)(0xFFFFu - (uint32_t)(m & 0xFFFFu));
            if (q0 == m) q0 = 0; else if (q1 == m) q1 = 0;
            else if (q2 == m) q2 = 0; else if (q3 == m) q3 = 0;
        }
    }
    __syncthreads();
}

__global__ __launch_bounds__(NTHREADS)
void topk_jsd_kernel(const float* __restrict__ p, const float* __restrict__ q,
                     float* __restrict__ out, int V)
{
    __shared__ u64 cand[CAP];
    __shared__ uint32_t refs[CAPREF];
    __shared__ u64 s_merge[4 * KTOP];
    __shared__ float s_f[8];
    __shared__ uint32_t s_cnt, s_ref;
    __shared__ uint16_t topP[KTOP];
    __shared__ uint16_t topQ[KTOP];
    __shared__ uint16_t s_union[2 * KTOP];
    __shared__ int s_nu;

    const int row = blockIdx.x;
    const int tid = threadIdx.x;
    const float* prow = p + (size_t)row * (size_t)V;
    const float* qrow = q + (size_t)row * (size_t)V;

    // ---- sample phase: max of first 2048 elems (stays L2-warm) ----
    int smp = V < 2048 ? V : 2048;
    float msP = 0.f, msQ = 0.f;
    for (int i = tid; i < smp; i += NTHREADS) {
        msP = fmaxf(msP, prow[i]);
        msQ = fmaxf(msQ, qrow[i]);
    }
    float MsP = block_max(msP, s_f, tid);
    float MsQ = block_max(msQ, s_f, tid);

    // target ~150 candidates: 128/V + sample-max bias compensation 1/smp
    float eps0 = fminf(128.f / (float)V + 1.f / (float)smp, 0.5f);

    // ---- P: collect + exact top-50 ----
    {
        float eps = eps0;
        int nc = collect_fast(prow, V, MsP * (1.f - eps), cand, refs, &s_cnt, &s_ref, tid);
        if (nc < 0) nc = collect_direct(prow, V, MsP * (1.f - eps), cand, &s_cnt, tid);
        for (int a = 0; a < 10 && (nc < KTOP || nc > CAP); ++a) {
            eps = (nc > CAP) ? eps * 0.25f : fminf(eps * 4.f, 1.f);
            nc = collect_direct(prow, V, MsP * (1.f - eps), cand, &s_cnt, tid);
        }
        if (nc > CAP) nc = CAP;
        find_topk(cand, nc, topP, s_merge, tid);
    }
    // ---- Q: collect + exact top-50 (reuses cand/refs) ----
    {
        float eps = eps0;
        int nc = collect_fast(qrow, V, MsQ * (1.f - eps), cand, refs, &s_cnt, &s_ref, tid);
        if (nc < 0) nc = collect_direct(qrow, V, MsQ * (1.f - eps), cand, &s_cnt, tid);
        for (int a = 0; a < 10 && (nc < KTOP || nc > CAP); ++a) {
            eps = (nc > CAP) ? eps * 0.25f : fminf(eps * 4.f, 1.f);
            nc = collect_direct(qrow, V, MsQ * (1.f - eps), cand, &s_cnt, tid);
        }
        if (nc > CAP) nc = CAP;
        find_topk(cand, nc, topQ, s_merge, tid);
    }

    // ---- union of index sets (wave 0) ----
    if (tid < KTOP) s_union[tid] = topP[tid];
    __syncthreads();
    if (tid < 64) {
        bool fresh = false; uint16_t qi = 0;
        if (tid < KTOP) {
            qi = topQ[tid]; fresh = true;
            for (int j = 0; j < KTOP; ++j) if (topP[j] == qi) fresh = false;
        }
        unsigned long long mb = __ballot(fresh);
        int pos = __popcll(mb & ((1ull << tid) - 1ull));
        if (fresh) s_union[KTOP + pos] = qi;
        if (tid == 0) s_nu = KTOP + __popcll(mb);
    }
    __syncthreads();
    int nu = s_nu;

    // ---- gather union values ----
    float pv = 0.f, qv = 0.f;
    if (tid < nu) {
        int ui = s_union[tid];
        pv = prow[ui];
        qv = qrow[ui];
    }

    // ---- block-reduce masked sums ----
    float sp = pv, sq = qv;
    for (int off = 32; off; off >>= 1) { sp += __shfl_down(sp, off); sq += __shfl_down(sq, off); }
    int wid = tid >> 6;
    if ((tid & 63) == 0) { s_f[wid] = sp; s_f[4 + wid] = sq; }
    __syncthreads();
    if (tid == 0) {
        float a = 0.f, b = 0.f;
        for (int w = 0; w < NTHREADS / 64; ++w) { a += s_f[w]; b += s_f[4 + w]; }
        s_f[0] = a; s_f[4] = b;
    }
    __syncthreads();
    float sump = s_f[0], sumq = s_f[4];
    __syncthreads();

    // ---- JSD over union (identical formula to validated kernels) ----
    float term = 0.f;
    if (tid < nu) {
        float pn = pv / (sump + EPSV);
        float qn = qv / (sumq + EPSV);
        float mn = 0.5f * (pn + qn);
        float ps = pn + EPSV, qs = qn + EPSV, ms = mn + EPSV;
        term = 0.5f * (ps * logf(ps / ms) + qs * logf(qs / ms));
    }
    for (int off = 32; off; off >>= 1) term += __shfl_down(term, off);
    if ((tid & 63) == 0) s_f[wid] = term;
    __syncthreads();
    if (tid == 0) {
        float a = 0.f;
        for (int w = 0; w < NTHREADS / 64; ++w) a += s_f[w];
        out[row] = a;
    }
}

extern "C" void kernel_launch(void* const* d_in, const int* in_sizes, int n_in,
                              void* d_out, int out_size, void* d_ws, size_t ws_size,
                              hipStream_t stream) {
    const float* p = (const float*)d_in[0];
    const float* q = (const float*)d_in[1];
    float* out = (float*)d_out;
    if (out_size <= 0) return;
    int N = out_size;            // B*S rows
    int V = in_sizes[0] / N;     // vocab size
    topk_jsd_kernel<<<dim3(N), dim3(NTHREADS), 0, stream>>>(p, q, out, V);
}